// Round 1
// baseline (6664.812 us; speedup 1.0000x reference)
//
#include <hip/hip_runtime.h>
#include <hip/hip_bf16.h>

// Problem constants
constexpr int B   = 64;
constexpr int NF  = 196;
constexpr int ENC = 2048;
constexpr int DEC = 512;
constexpr int ATT = 512;
constexpr int V   = 30000;
constexpr int EMB = 512;
constexpr int T   = 24;           // captions.shape[1] - 1
constexpr int KCAT = EMB + ENC + DEC;   // 3072
constexpr int NGATES = 4 * DEC;         // 2048
constexpr int NSPLIT = 16;
constexpr int KSPLIT = KCAT / NSPLIT;   // 192

#define DEV static __device__ __forceinline__

DEV float fast_tanh(float x) {
    float e = __expf(2.f * x);
    return 1.f - 2.f / (e + 1.f);   // handles +-inf gracefully
}
DEV float fast_sigmoid(float x) {
    return 1.f / (1.f + __expf(-x));
}

// ---------------------------------------------------------------- embeds
__global__ __launch_bounds__(256) void embed_gather(
    const float* __restrict__ emb, const int* __restrict__ captions,
    float* __restrict__ embeds) {
    int idx = blockIdx.x * 256 + threadIdx.x;   // B*T*EMB = 786432
    if (idx >= B * T * EMB) return;
    int j  = idx % EMB;
    int bt = idx / EMB;
    int t = bt % T, b = bt / T;
    int tok = captions[b * 25 + t];
    embeds[idx] = emb[(size_t)tok * EMB + j];
}

// ---------------------------------------------------------------- mean over NF
__global__ __launch_bounds__(256) void mean_feat(
    const float* __restrict__ feat, float* __restrict__ mean_f) {
    int e = blockIdx.x * 256 + threadIdx.x;   // grid (8, 64)
    int b = blockIdx.y;
    const float* p = feat + (size_t)b * NF * ENC + e;
    float s = 0.f;
    #pragma unroll 4
    for (int f = 0; f < NF; ++f) s += p[(size_t)f * ENC];
    mean_f[b * ENC + e] = s * (1.f / NF);
}

// ---------------------------------------------------------------- generic fp32 GEMM + bias
// C[M,N] = A[M,K] @ B[K,N] + bias[N].  BM=BN=128, BK=16, 256 thr, 8x8/thread.
__global__ __launch_bounds__(256) void gemm_bias(
    const float* __restrict__ A, const float* __restrict__ Bm,
    const float* __restrict__ bias, float* __restrict__ C,
    int M, int N, int K) {
    constexpr int BM = 128, BN = 128, BK = 16;
    __shared__ float As[BK][BM + 4];
    __shared__ float Bs[BK][BN + 4];
    const int tid = threadIdx.x;
    const int tx = tid & 15, ty = tid >> 4;
    const int row0 = blockIdx.y * BM, col0 = blockIdx.x * BN;
    float acc[8][8] = {};
    for (int k0 = 0; k0 < K; k0 += BK) {
        #pragma unroll
        for (int i = 0; i < 8; ++i) {             // A tile 128x16
            int e = tid + i * 256;
            int r = e >> 4, c = e & 15;
            int gr = row0 + r;
            As[c][r] = (gr < M) ? A[(size_t)gr * K + k0 + c] : 0.f;
        }
        #pragma unroll
        for (int i = 0; i < 8; ++i) {             // B tile 16x128
            int e = tid + i * 256;
            int r = e >> 7, c = e & 127;
            int gc = col0 + c;
            Bs[r][c] = (gc < N) ? Bm[(size_t)(k0 + r) * N + gc] : 0.f;
        }
        __syncthreads();
        #pragma unroll
        for (int kk = 0; kk < BK; ++kk) {
            const float4 a0 = *reinterpret_cast<const float4*>(&As[kk][ty * 8]);
            const float4 a1 = *reinterpret_cast<const float4*>(&As[kk][ty * 8 + 4]);
            const float4 b0 = *reinterpret_cast<const float4*>(&Bs[kk][tx * 8]);
            const float4 b1 = *reinterpret_cast<const float4*>(&Bs[kk][tx * 8 + 4]);
            const float av[8] = {a0.x, a0.y, a0.z, a0.w, a1.x, a1.y, a1.z, a1.w};
            const float bv[8] = {b0.x, b0.y, b0.z, b0.w, b1.x, b1.y, b1.z, b1.w};
            #pragma unroll
            for (int m = 0; m < 8; ++m)
                #pragma unroll
                for (int n = 0; n < 8; ++n)
                    acc[m][n] += av[m] * bv[n];
        }
        __syncthreads();
    }
    #pragma unroll
    for (int m = 0; m < 8; ++m) {
        int gr = row0 + ty * 8 + m;
        if (gr >= M) continue;
        #pragma unroll
        for (int n = 0; n < 8; ++n) {
            int gc = col0 + tx * 8 + n;
            if (gc < N) C[(size_t)gr * N + gc] = acc[m][n] + bias[gc];
        }
    }
}

// ---------------------------------------------------------------- attention: w_ah + scores + softmax
__global__ __launch_bounds__(256) void attn_kernel(
    const float* __restrict__ h, const float* __restrict__ Ww,
    const float* __restrict__ Wb, const float* __restrict__ Aw,
    const float* __restrict__ Ab, const float* __restrict__ u_hs,
    float* __restrict__ alpha_ws, float* __restrict__ alphas_out, int t) {
    const int b = blockIdx.x;
    const int tid = threadIdx.x;
    const int lane = tid & 63, wv = tid >> 6;
    __shared__ float h_s[DEC];
    __shared__ float wah_s[ATT];
    __shared__ float aw_s[ATT];
    __shared__ float sc_s[NF];
    __shared__ float wred[4];

    for (int i = tid; i < DEC; i += 256) h_s[i] = h[b * DEC + i];
    for (int i = tid; i < ATT; i += 256) aw_s[i] = Aw[i];
    __syncthreads();

    // w_ah[j] = h . Ww[:,j] + Wb[j]
    for (int j = tid; j < ATT; j += 256) {
        float s = Wb[j];
        #pragma unroll 8
        for (int k = 0; k < DEC; ++k) s += h_s[k] * Ww[(size_t)k * ATT + j];
        wah_s[j] = s;
    }
    __syncthreads();

    // scores[f] = tanh(u_hs[b,f,:] + w_ah) . Aw + Ab
    const float ab0 = Ab[0];
    for (int f = wv; f < NF; f += 4) {
        const float* up = u_hs + ((size_t)b * NF + f) * ATT;
        float s = 0.f;
        #pragma unroll
        for (int k = lane; k < ATT; k += 64)
            s += fast_tanh(up[k] + wah_s[k]) * aw_s[k];
        #pragma unroll
        for (int o = 32; o > 0; o >>= 1) s += __shfl_xor(s, o);
        if (lane == 0) sc_s[f] = s + ab0;
    }
    __syncthreads();

    // softmax over NF=196
    float v = (tid < NF) ? sc_s[tid] : -INFINITY;
    float m = v;
    #pragma unroll
    for (int o = 32; o > 0; o >>= 1) m = fmaxf(m, __shfl_xor(m, o));
    if (lane == 0) wred[wv] = m;
    __syncthreads();
    m = fmaxf(fmaxf(wred[0], wred[1]), fmaxf(wred[2], wred[3]));
    __syncthreads();
    float e = (tid < NF) ? __expf(v - m) : 0.f;
    float ssum = e;
    #pragma unroll
    for (int o = 32; o > 0; o >>= 1) ssum += __shfl_xor(ssum, o);
    if (lane == 0) wred[wv] = ssum;
    __syncthreads();
    float tot = wred[0] + wred[1] + wred[2] + wred[3];
    if (tid < NF) {
        float a = e / tot;
        alpha_ws[b * NF + tid] = a;
        alphas_out[((size_t)b * T + t) * NF + tid] = a;
    }
}

// ---------------------------------------------------------------- context = alpha @ features
__global__ __launch_bounds__(256) void context_kernel(
    const float* __restrict__ alpha, const float* __restrict__ feat,
    float* __restrict__ ctx) {
    int b = blockIdx.y;
    int e = blockIdx.x * 256 + threadIdx.x;   // grid (8, 64)
    __shared__ float a_s[NF];
    for (int i = threadIdx.x; i < NF; i += 256) a_s[i] = alpha[b * NF + i];
    __syncthreads();
    const float* fp = feat + (size_t)b * NF * ENC + e;
    float s = 0.f;
    #pragma unroll 4
    for (int f = 0; f < NF; ++f) s += a_s[f] * fp[(size_t)f * ENC];
    ctx[b * ENC + e] = s;
}

// ---------------------------------------------------------------- gates GEMM, split-K
// A[b,k] = [embeds_t | context | h][b,k], Bsel = [W_ih ; W_hh].  partials[s][b][n]
DEV float xcat_at(const float* __restrict__ embeds, const float* __restrict__ ctx,
                  const float* __restrict__ h, int b, int k, int t) {
    if (k < EMB)       return embeds[((size_t)b * T + t) * EMB + k];
    if (k < EMB + ENC) return ctx[b * ENC + (k - EMB)];
    return h[b * DEC + (k - EMB - ENC)];
}

__global__ __launch_bounds__(256) void gates_splitk(
    const float* __restrict__ embeds, const float* __restrict__ ctx,
    const float* __restrict__ h, const float* __restrict__ Wih,
    const float* __restrict__ Whh, float* __restrict__ part, int t) {
    constexpr int BK = 16;
    __shared__ float As[BK][64 + 4];
    __shared__ float Bs[BK][128 + 4];
    const int tid = threadIdx.x;
    const int tx = tid & 15, ty = tid >> 4;
    const int col0 = blockIdx.x * 128;        // grid (16,1,16)
    const int split = blockIdx.z;
    const int kbase = split * KSPLIT;
    float acc[4][8] = {};
    for (int k0 = 0; k0 < KSPLIT; k0 += BK) {
        #pragma unroll
        for (int i = 0; i < 4; ++i) {         // A tile 64x16
            int e = tid + i * 256;
            int r = e >> 4, c = e & 15;
            As[c][r] = xcat_at(embeds, ctx, h, r, kbase + k0 + c, t);
        }
        #pragma unroll
        for (int i = 0; i < 8; ++i) {         // B tile 16x128
            int e = tid + i * 256;
            int r = e >> 7, c = e & 127;
            int k = kbase + k0 + r;
            int gc = col0 + c;
            Bs[r][c] = (k < EMB + ENC)
                           ? Wih[(size_t)k * NGATES + gc]
                           : Whh[(size_t)(k - EMB - ENC) * NGATES + gc];
        }
        __syncthreads();
        #pragma unroll
        for (int kk = 0; kk < BK; ++kk) {
            const float4 a  = *reinterpret_cast<const float4*>(&As[kk][ty * 4]);
            const float4 b0 = *reinterpret_cast<const float4*>(&Bs[kk][tx * 8]);
            const float4 b1 = *reinterpret_cast<const float4*>(&Bs[kk][tx * 8 + 4]);
            const float av[4] = {a.x, a.y, a.z, a.w};
            const float bv[8] = {b0.x, b0.y, b0.z, b0.w, b1.x, b1.y, b1.z, b1.w};
            #pragma unroll
            for (int m = 0; m < 4; ++m)
                #pragma unroll
                for (int n = 0; n < 8; ++n)
                    acc[m][n] += av[m] * bv[n];
        }
        __syncthreads();
    }
    float* p = part + (size_t)split * B * NGATES;
    #pragma unroll
    for (int m = 0; m < 4; ++m)
        #pragma unroll
        for (int n = 0; n < 8; ++n)
            p[(size_t)(ty * 4 + m) * NGATES + col0 + tx * 8 + n] = acc[m][n];
}

// ---------------------------------------------------------------- LSTM pointwise (reduce split-K)
__global__ __launch_bounds__(256) void lstm_kernel(
    const float* __restrict__ part, const float* __restrict__ b_ih,
    const float* __restrict__ b_hh, float* __restrict__ h,
    float* __restrict__ c, float* __restrict__ H, int t) {
    int idx = blockIdx.x * 256 + threadIdx.x;  // B*DEC = 32768
    int j = idx % DEC, b = idx / DEC;
    float gi = b_ih[j]           + b_hh[j];
    float gf = b_ih[j + DEC]     + b_hh[j + DEC];
    float gg = b_ih[j + 2 * DEC] + b_hh[j + 2 * DEC];
    float go = b_ih[j + 3 * DEC] + b_hh[j + 3 * DEC];
    #pragma unroll
    for (int s = 0; s < NSPLIT; ++s) {
        const float* p = part + ((size_t)s * B + b) * NGATES;
        gi += p[j];
        gf += p[j + DEC];
        gg += p[j + 2 * DEC];
        go += p[j + 3 * DEC];
    }
    float cn = fast_sigmoid(gf) * c[idx] + fast_sigmoid(gi) * fast_tanh(gg);
    float hn = fast_sigmoid(go) * fast_tanh(cn);
    c[idx] = cn;
    h[idx] = hn;
    H[((size_t)b * T + t) * DEC + j] = hn;
}

// ---------------------------------------------------------------- launch
extern "C" void kernel_launch(void* const* d_in, const int* in_sizes, int n_in,
                              void* d_out, int out_size, void* d_ws, size_t ws_size,
                              hipStream_t stream) {
    const float* features = (const float*)d_in[0];
    const int*   captions = (const int*)d_in[1];
    const float* emb      = (const float*)d_in[2];
    const float* Uw       = (const float*)d_in[3];
    const float* Ub       = (const float*)d_in[4];
    const float* Ww       = (const float*)d_in[5];
    const float* Wb       = (const float*)d_in[6];
    const float* Aw       = (const float*)d_in[7];
    const float* Ab       = (const float*)d_in[8];
    const float* ih_w     = (const float*)d_in[9];
    const float* ih_b     = (const float*)d_in[10];
    const float* ic_w     = (const float*)d_in[11];
    const float* ic_b     = (const float*)d_in[12];
    const float* W_ih     = (const float*)d_in[13];
    const float* b_ih     = (const float*)d_in[14];
    const float* W_hh     = (const float*)d_in[15];
    const float* b_hh     = (const float*)d_in[16];
    const float* fcn_w    = (const float*)d_in[17];
    const float* fcn_b    = (const float*)d_in[18];

    float* preds  = (float*)d_out;                       // (B,T,V)
    float* alphas = preds + (size_t)B * T * V;           // (B,T,NF)

    // workspace layout (floats)
    float* ws      = (float*)d_ws;
    float* embeds  = ws;                                  // 786432
    float* meanf   = embeds + (size_t)B * T * EMB;        // 131072
    float* h       = meanf + (size_t)B * ENC;             // 32768
    float* c       = h + (size_t)B * DEC;                 // 32768
    float* uhs     = c + (size_t)B * DEC;                 // 6422528
    float* alpha   = uhs + (size_t)B * NF * ATT;          // 12544
    float* ctx     = alpha + (size_t)B * NF;              // 131072
    float* part    = ctx + (size_t)B * ENC;               // 2097152
    float* Hbuf    = part + (size_t)NSPLIT * B * NGATES;  // 786432

    embed_gather<<<(B * T * EMB + 255) / 256, 256, 0, stream>>>(emb, captions, embeds);
    mean_feat<<<dim3(ENC / 256, B), 256, 0, stream>>>(features, meanf);
    gemm_bias<<<dim3(DEC / 128, 1), 256, 0, stream>>>(meanf, ih_w, ih_b, h, B, DEC, ENC);
    gemm_bias<<<dim3(DEC / 128, 1), 256, 0, stream>>>(meanf, ic_w, ic_b, c, B, DEC, ENC);
    // u_hs = features @ Uw + Ub : (B*NF, ATT)
    gemm_bias<<<dim3(ATT / 128, (B * NF) / 128), 256, 0, stream>>>(
        features, Uw, Ub, uhs, B * NF, ATT, ENC);

    for (int t = 0; t < T; ++t) {
        attn_kernel<<<B, 256, 0, stream>>>(h, Ww, Wb, Aw, Ab, uhs, alpha, alphas, t);
        context_kernel<<<dim3(ENC / 256, B), 256, 0, stream>>>(alpha, features, ctx);
        gates_splitk<<<dim3(NGATES / 128, 1, NSPLIT), 256, 0, stream>>>(
            embeds, ctx, h, W_ih, W_hh, part, t);
        lstm_kernel<<<(B * DEC) / 256, 256, 0, stream>>>(part, b_ih, b_hh, h, c, Hbuf, t);
    }

    // preds = H @ fcn_w + fcn_b : (B*T, V)
    gemm_bias<<<dim3((V + 127) / 128, (B * T) / 128), 256, 0, stream>>>(
        Hbuf, fcn_w, fcn_b, preds, B * T, V, DEC);
}

// Round 3
// 4451.456 us; speedup vs baseline: 1.4972x; 1.4972x over previous
//
#include <hip/hip_runtime.h>
#include <hip/hip_bf16.h>

constexpr int B   = 64;
constexpr int NF  = 196;
constexpr int ENC = 2048;
constexpr int DEC = 512;
constexpr int ATT = 512;
constexpr int V   = 30000;
constexpr int EMB = 512;
constexpr int T   = 24;
constexpr int NGATES = 4 * DEC;        // 2048
constexpr int KSTEP = ENC + DEC;       // 2560: [ctx | h]
constexpr int NSPLIT = 8;
constexpr int KSPLIT = KSTEP / NSPLIT; // 320

typedef short s16x8 __attribute__((ext_vector_type(8)));   // 8 bf16 (guide-verified MFMA frag type)
typedef float f32x4 __attribute__((ext_vector_type(4)));
typedef unsigned short ushort;
typedef ushort u16x8 __attribute__((ext_vector_type(8)));

#define DEV static __device__ __forceinline__

DEV float fast_tanh(float x) { float e = __expf(2.f * x); return 1.f - 2.f / (e + 1.f); }
DEV float fast_sigmoid(float x) { return 1.f / (1.f + __expf(-x)); }
DEV ushort f2bf(float f) {
    unsigned u = __float_as_uint(f);
    unsigned r = u + 0x7FFFu + ((u >> 16) & 1u);
    return (ushort)(r >> 16);
}
DEV float bf2f(ushort u) { return __uint_as_float(((unsigned)u) << 16); }

// ============================================================ MFMA GEMM
// C[M,N] = A[M,K] @ BT[N,K]^T + bias[N].  A: bf16(ushort) or f32 (AF32).
// Output f32 or bf16 (OUT16). BM=BN=128, BK=32, 4 waves, 64x64/wave.
// LDS [128][32] bf16, 16B-slot XOR swizzle: slot ^= (row>>1)&3.
template <bool AF32, bool OUT16>
__global__ __launch_bounds__(256) void mfma_gemm(
    const void* __restrict__ Aptr, const ushort* __restrict__ BT,
    const float* __restrict__ bias, void* __restrict__ Cptr,
    int M, int N, int K) {
    __shared__ ushort As[128 * 32];
    __shared__ ushort Bs[128 * 32];
    const int tid = threadIdx.x;
    const int lane = tid & 63;
    const int w = tid >> 6;
    const int wr = (w >> 1) * 64, wc = (w & 1) * 64;
    const int row0 = blockIdx.y * 128, col0 = blockIdx.x * 128;
    const int ln15 = lane & 15, lq = lane >> 4;

    f32x4 acc[4][4] = {};

    for (int k0 = 0; k0 < K; k0 += 32) {
        #pragma unroll
        for (int i = 0; i < 2; ++i) {             // A tile 128x32
            int u = tid + i * 256;
            int r = u >> 2, s = u & 3;
            u16x8 v;
            if (AF32) {
                const float* src = (const float*)Aptr + (size_t)(row0 + r) * K + k0 + s * 8;
                #pragma unroll
                for (int j = 0; j < 8; ++j) v[j] = f2bf(src[j]);
            } else {
                v = *(const u16x8*)((const ushort*)Aptr + (size_t)(row0 + r) * K + k0 + s * 8);
            }
            *(u16x8*)&As[r * 32 + ((s ^ ((r >> 1) & 3)) * 8)] = v;
        }
        #pragma unroll
        for (int i = 0; i < 2; ++i) {             // B tile 128x32 (rows are N cols)
            int u = tid + i * 256;
            int r = u >> 2, s = u & 3;
            int gr = col0 + r; if (gr >= N) gr = N - 1;
            u16x8 v = *(const u16x8*)(BT + (size_t)gr * K + k0 + s * 8);
            *(u16x8*)&Bs[r * 32 + ((s ^ ((r >> 1) & 3)) * 8)] = v;
        }
        __syncthreads();

        s16x8 af[4], bfr[4];
        #pragma unroll
        for (int m = 0; m < 4; ++m) {
            int rr = wr + m * 16 + ln15;
            af[m] = *(const s16x8*)&As[rr * 32 + ((lq ^ ((rr >> 1) & 3)) * 8)];
        }
        #pragma unroll
        for (int n = 0; n < 4; ++n) {
            int rr = wc + n * 16 + ln15;
            bfr[n] = *(const s16x8*)&Bs[rr * 32 + ((lq ^ ((rr >> 1) & 3)) * 8)];
        }
        #pragma unroll
        for (int m = 0; m < 4; ++m)
            #pragma unroll
            for (int n = 0; n < 4; ++n)
                acc[m][n] = __builtin_amdgcn_mfma_f32_16x16x32_bf16(af[m], bfr[n], acc[m][n], 0, 0, 0);
        __syncthreads();
    }

    // D: col = lane&15, row = (lane>>4)*4 + i (verified layout)
    #pragma unroll
    for (int m = 0; m < 4; ++m) {
        #pragma unroll
        for (int n = 0; n < 4; ++n) {
            int col = col0 + wc + n * 16 + ln15;
            if (col >= N) continue;
            float bv = bias[col];
            #pragma unroll
            for (int i = 0; i < 4; ++i) {
                int row = row0 + wr + m * 16 + lq * 4 + i;
                float v = acc[m][n][i] + bv;
                if (OUT16) ((ushort*)Cptr)[(size_t)row * N + col] = f2bf(v);
                else       ((float*)Cptr)[(size_t)row * N + col] = v;
            }
        }
    }
}

// ============================================================ transpose f32 -> bf16: dst[Ccols][R] from src[R][Ccols]
__global__ __launch_bounds__(256) void trans_bf16(
    const float* __restrict__ src, ushort* __restrict__ dst, int R, int Ccols) {
    __shared__ float tile[32][33];
    int tx = threadIdx.x & 31, ty = threadIdx.x >> 5;
    int c0 = blockIdx.x * 32, r0 = blockIdx.y * 32;
    #pragma unroll
    for (int i = 0; i < 4; ++i) {
        int r = r0 + ty + i * 8, c = c0 + tx;
        tile[ty + i * 8][tx] = (r < R && c < Ccols) ? src[(size_t)r * Ccols + c] : 0.f;
    }
    __syncthreads();
    #pragma unroll
    for (int i = 0; i < 4; ++i) {
        int dc = c0 + ty + i * 8;
        int dr = r0 + tx;
        if (dc < Ccols && dr < R) dst[(size_t)dc * R + dr] = f2bf(tile[tx][ty + i * 8]);
    }
}

// ============================================================ setup kernels
__global__ __launch_bounds__(256) void embed_gather16(
    const float* __restrict__ emb, const int* __restrict__ captions,
    ushort* __restrict__ emb16) {
    int idx = blockIdx.x * 256 + threadIdx.x;
    if (idx >= B * T * EMB) return;
    int j = idx % EMB;
    int bt = idx / EMB;
    int t = bt % T, b = bt / T;
    int tok = captions[b * 25 + t];
    emb16[idx] = f2bf(emb[(size_t)tok * EMB + j]);
}

__global__ __launch_bounds__(256) void bsum_kernel(
    const float* __restrict__ b_ih, const float* __restrict__ b_hh,
    float* __restrict__ bsum) {
    int j = blockIdx.x * 256 + threadIdx.x;
    if (j < NGATES) bsum[j] = b_ih[j] + b_hh[j];
}

__global__ __launch_bounds__(256) void mean_feat(
    const float* __restrict__ feat, float* __restrict__ mean_f) {
    int e = blockIdx.x * 256 + threadIdx.x;
    int b = blockIdx.y;
    const float* p = feat + (size_t)b * NF * ENC + e;
    float s = 0.f;
    #pragma unroll 4
    for (int f = 0; f < NF; ++f) s += p[(size_t)f * ENC];
    mean_f[b * ENC + e] = s * (1.f / NF);
}

// fp32 GEMM for tiny h0/c0 init (M=64)
__global__ __launch_bounds__(256) void gemm_bias(
    const float* __restrict__ A, const float* __restrict__ Bm,
    const float* __restrict__ bias, float* __restrict__ C,
    int M, int N, int K) {
    constexpr int BM = 128, BN = 128, BK = 16;
    __shared__ float As[BK][BM + 4];
    __shared__ float Bs[BK][BN + 4];
    const int tid = threadIdx.x;
    const int tx = tid & 15, ty = tid >> 4;
    const int row0 = blockIdx.y * BM, col0 = blockIdx.x * BN;
    float acc[8][8] = {};
    for (int k0 = 0; k0 < K; k0 += BK) {
        #pragma unroll
        for (int i = 0; i < 8; ++i) {
            int e = tid + i * 256;
            int r = e >> 4, c = e & 15;
            int gr = row0 + r;
            As[c][r] = (gr < M) ? A[(size_t)gr * K + k0 + c] : 0.f;
        }
        #pragma unroll
        for (int i = 0; i < 8; ++i) {
            int e = tid + i * 256;
            int r = e >> 7, c = e & 127;
            int gc = col0 + c;
            Bs[r][c] = (gc < N) ? Bm[(size_t)(k0 + r) * N + gc] : 0.f;
        }
        __syncthreads();
        #pragma unroll
        for (int kk = 0; kk < BK; ++kk) {
            const float4 a0 = *reinterpret_cast<const float4*>(&As[kk][ty * 8]);
            const float4 a1 = *reinterpret_cast<const float4*>(&As[kk][ty * 8 + 4]);
            const float4 b0 = *reinterpret_cast<const float4*>(&Bs[kk][tx * 8]);
            const float4 b1 = *reinterpret_cast<const float4*>(&Bs[kk][tx * 8 + 4]);
            const float av[8] = {a0.x, a0.y, a0.z, a0.w, a1.x, a1.y, a1.z, a1.w};
            const float bv[8] = {b0.x, b0.y, b0.z, b0.w, b1.x, b1.y, b1.z, b1.w};
            #pragma unroll
            for (int m = 0; m < 8; ++m)
                #pragma unroll
                for (int n = 0; n < 8; ++n)
                    acc[m][n] += av[m] * bv[n];
        }
        __syncthreads();
    }
    #pragma unroll
    for (int m = 0; m < 8; ++m) {
        int gr = row0 + ty * 8 + m;
        if (gr >= M) continue;
        #pragma unroll
        for (int n = 0; n < 8; ++n) {
            int gc = col0 + tx * 8 + n;
            if (gc < N) C[(size_t)gr * N + gc] = acc[m][n] + bias[gc];
        }
    }
}

// ============================================================ per-step kernels
__global__ __launch_bounds__(256) void wah_kernel(
    const float* __restrict__ h, const float* __restrict__ Ww,
    const float* __restrict__ Wb, float* __restrict__ wah) {
    int b = blockIdx.x;
    int tid = threadIdx.x;
    __shared__ float h_s[DEC];
    for (int i = tid; i < DEC; i += 256) h_s[i] = h[b * DEC + i];
    __syncthreads();
    for (int j = tid; j < ATT; j += 256) {
        float s = Wb[j];
        #pragma unroll 8
        for (int k = 0; k < DEC; ++k) s += h_s[k] * Ww[(size_t)k * ATT + j];
        wah[b * ATT + j] = s;
    }
}

__global__ __launch_bounds__(256) void scores_kernel(
    const float* __restrict__ u_hs, const float* __restrict__ wah,
    const float* __restrict__ Aw, const float* __restrict__ Ab,
    float* __restrict__ scores) {
    const int b = blockIdx.y;
    const int fc = blockIdx.x;       // 7 chunks of 28
    const int tid = threadIdx.x;
    const int lane = tid & 63, wv = tid >> 6;
    __shared__ float wah_s[ATT];
    __shared__ float aw_s[ATT];
    for (int i = tid; i < ATT; i += 256) { wah_s[i] = wah[b * ATT + i]; aw_s[i] = Aw[i]; }
    __syncthreads();
    const float ab0 = Ab[0];
    #pragma unroll
    for (int i = 0; i < 7; ++i) {
        int f = fc * 28 + wv * 7 + i;
        const float* up = u_hs + ((size_t)b * NF + f) * ATT;
        float s = 0.f;
        #pragma unroll
        for (int k = lane; k < ATT; k += 64)
            s += fast_tanh(up[k] + wah_s[k]) * aw_s[k];
        #pragma unroll
        for (int o = 32; o > 0; o >>= 1) s += __shfl_xor(s, o);
        if (lane == 0) scores[b * NF + f] = s + ab0;
    }
}

__global__ __launch_bounds__(256) void smctx_kernel(
    const float* __restrict__ scores, const float* __restrict__ feat,
    float* __restrict__ ctx, float* __restrict__ alphas_out, int t) {
    const int b = blockIdx.y;
    const int ec = blockIdx.x;      // 8 chunks of 256
    const int tid = threadIdx.x;
    const int lane = tid & 63, wv = tid >> 6;
    __shared__ float a_s[NF];
    __shared__ float red[8];
    float v = (tid < NF) ? scores[b * NF + tid] : -INFINITY;
    float m = v;
    #pragma unroll
    for (int o = 32; o > 0; o >>= 1) m = fmaxf(m, __shfl_xor(m, o));
    if (lane == 0) red[wv] = m;
    __syncthreads();
    m = fmaxf(fmaxf(red[0], red[1]), fmaxf(red[2], red[3]));
    float e = (tid < NF) ? __expf(v - m) : 0.f;
    float ss = e;
    #pragma unroll
    for (int o = 32; o > 0; o >>= 1) ss += __shfl_xor(ss, o);
    if (lane == 0) red[4 + wv] = ss;
    __syncthreads();
    float tot = red[4] + red[5] + red[6] + red[7];
    if (tid < NF) {
        float a = e / tot;
        a_s[tid] = a;
        if (ec == 0) alphas_out[((size_t)b * T + t) * NF + tid] = a;
    }
    __syncthreads();
    int eidx = ec * 256 + tid;
    const float* fp = feat + (size_t)b * NF * ENC + eidx;
    float s = 0.f;
    #pragma unroll 4
    for (int f = 0; f < NF; ++f) s += a_s[f] * fp[(size_t)f * ENC];
    ctx[b * ENC + eidx] = s;
}

DEV float xcat(const float* __restrict__ ctx, const float* __restrict__ h, int b, int k) {
    return (k < ENC) ? ctx[b * ENC + k] : h[b * DEC + (k - ENC)];
}

__global__ __launch_bounds__(256) void gates_splitk(
    const float* __restrict__ ctx, const float* __restrict__ h,
    const float* __restrict__ Wih, const float* __restrict__ Whh,
    float* __restrict__ part) {
    constexpr int BK = 16;
    __shared__ float As[BK][64 + 4];
    __shared__ float Bs[BK][128 + 4];
    const int tid = threadIdx.x;
    const int tx = tid & 15, ty = tid >> 4;
    const int col0 = blockIdx.x * 128;
    const int split = blockIdx.z;
    const int kbase = split * KSPLIT;
    float acc[4][8] = {};
    for (int k0 = 0; k0 < KSPLIT; k0 += BK) {
        #pragma unroll
        for (int i = 0; i < 4; ++i) {
            int e = tid + i * 256;
            int r = e >> 4, c = e & 15;
            As[c][r] = xcat(ctx, h, r, kbase + k0 + c);
        }
        #pragma unroll
        for (int i = 0; i < 8; ++i) {
            int e = tid + i * 256;
            int r = e >> 7, c = e & 127;
            int k = kbase + k0 + r;
            int gc = col0 + c;
            Bs[r][c] = (k < ENC) ? Wih[(size_t)(EMB + k) * NGATES + gc]
                                 : Whh[(size_t)(k - ENC) * NGATES + gc];
        }
        __syncthreads();
        #pragma unroll
        for (int kk = 0; kk < BK; ++kk) {
            const float4 a  = *reinterpret_cast<const float4*>(&As[kk][ty * 4]);
            const float4 b0 = *reinterpret_cast<const float4*>(&Bs[kk][tx * 8]);
            const float4 b1 = *reinterpret_cast<const float4*>(&Bs[kk][tx * 8 + 4]);
            const float av[4] = {a.x, a.y, a.z, a.w};
            const float bv[8] = {b0.x, b0.y, b0.z, b0.w, b1.x, b1.y, b1.z, b1.w};
            #pragma unroll
            for (int m = 0; m < 4; ++m)
                #pragma unroll
                for (int n = 0; n < 8; ++n)
                    acc[m][n] += av[m] * bv[n];
        }
        __syncthreads();
    }
    float* p = part + (size_t)split * B * NGATES;
    #pragma unroll
    for (int m = 0; m < 4; ++m)
        #pragma unroll
        for (int n = 0; n < 8; ++n)
            p[(size_t)(ty * 4 + m) * NGATES + col0 + tx * 8 + n] = acc[m][n];
}

__global__ __launch_bounds__(256) void lstm_kernel(
    const float* __restrict__ part, const ushort* __restrict__ egate,
    float* __restrict__ h, float* __restrict__ c,
    ushort* __restrict__ Hb16, int t) {
    int idx = blockIdx.x * 256 + threadIdx.x;   // B*DEC
    int j = idx % DEC, b = idx / DEC;
    const ushort* eg = egate + (size_t)(b * T + t) * NGATES;
    float gi = bf2f(eg[j]);
    float gf = bf2f(eg[j + DEC]);
    float gg = bf2f(eg[j + 2 * DEC]);
    float go = bf2f(eg[j + 3 * DEC]);
    #pragma unroll
    for (int s = 0; s < NSPLIT; ++s) {
        const float* p = part + ((size_t)s * B + b) * NGATES;
        gi += p[j];
        gf += p[j + DEC];
        gg += p[j + 2 * DEC];
        go += p[j + 3 * DEC];
    }
    float cn = fast_sigmoid(gf) * c[idx] + fast_sigmoid(gi) * fast_tanh(gg);
    float hn = fast_sigmoid(go) * fast_tanh(cn);
    c[idx] = cn;
    h[idx] = hn;
    Hb16[(size_t)(b * T + t) * DEC + j] = f2bf(hn);
}

// ============================================================ launch
extern "C" void kernel_launch(void* const* d_in, const int* in_sizes, int n_in,
                              void* d_out, int out_size, void* d_ws, size_t ws_size,
                              hipStream_t stream) {
    const float* features = (const float*)d_in[0];
    const int*   captions = (const int*)d_in[1];
    const float* emb      = (const float*)d_in[2];
    const float* Uw       = (const float*)d_in[3];
    const float* Ub       = (const float*)d_in[4];
    const float* Ww       = (const float*)d_in[5];
    const float* Wb       = (const float*)d_in[6];
    const float* Aw       = (const float*)d_in[7];
    const float* Ab       = (const float*)d_in[8];
    const float* ih_w     = (const float*)d_in[9];
    const float* ih_b     = (const float*)d_in[10];
    const float* ic_w     = (const float*)d_in[11];
    const float* ic_b     = (const float*)d_in[12];
    const float* W_ih     = (const float*)d_in[13];
    const float* b_ih     = (const float*)d_in[14];
    const float* W_hh     = (const float*)d_in[15];
    const float* b_hh     = (const float*)d_in[16];
    const float* fcn_w    = (const float*)d_in[17];
    const float* fcn_b    = (const float*)d_in[18];

    float* preds  = (float*)d_out;                 // (B,T,V)
    float* alphas = preds + (size_t)B * T * V;     // (B,T,NF)

    // ---- workspace layout (total 40,821,760 B <= 41.69 MB proven) ----
    char* base = (char*)d_ws;
    float* uhs    = (float*)base;                       // 25,690,112 B  (dead after loop)
    char* p = base + (size_t)B * NF * ATT * 4;
    ushort* egate = (ushort*)p;                          // 6,291,456 B   (dead after loop)
    p += (size_t)B * T * NGATES * 2;
    // shared region: part (loop) / UwT+WihT (setup) — 4,194,304 B
    char* Sreg = p;
    float*  part = (float*)Sreg;                         // 8*64*2048*4 = 4,194,304 B
    ushort* UwT  = (ushort*)Sreg;                        // 512*2048*2 = 2,097,152 B
    ushort* WihT = (ushort*)(Sreg + 2097152);            // 512*2048*2 = 2,097,152 B
    p += 4194304;
    float* ctx    = (float*)p;  p += (size_t)B * ENC * 4;
    float* meanf  = (float*)p;  p += (size_t)B * ENC * 4;
    float* h      = (float*)p;  p += (size_t)B * DEC * 4;
    float* c      = (float*)p;  p += (size_t)B * DEC * 4;
    float* wah    = (float*)p;  p += (size_t)B * ATT * 4;
    float* scores = (float*)p;  p += (size_t)B * NF * 4;
    float* bsum   = (float*)p;  p += (size_t)NGATES * 4;
    ushort* emb16 = (ushort*)p; p += (size_t)B * T * EMB * 2;
    ushort* Hb16  = (ushort*)p; p += (size_t)B * T * DEC * 2;
    // fcn_w^T (30,720,000 B) aliased over uhs+egate (31,981,568 B), used only after loop
    ushort* fcnwT = (ushort*)base;

    // ---- setup ----
    embed_gather16<<<(B * T * EMB + 255) / 256, 256, 0, stream>>>(emb, captions, emb16);
    bsum_kernel<<<(NGATES + 255) / 256, 256, 0, stream>>>(b_ih, b_hh, bsum);
    mean_feat<<<dim3(ENC / 256, B), 256, 0, stream>>>(features, meanf);
    gemm_bias<<<dim3(DEC / 128, 1), 256, 0, stream>>>(meanf, ih_w, ih_b, h, B, DEC, ENC);
    gemm_bias<<<dim3(DEC / 128, 1), 256, 0, stream>>>(meanf, ic_w, ic_b, c, B, DEC, ENC);

    trans_bf16<<<dim3((ATT + 31) / 32, (ENC + 31) / 32), 256, 0, stream>>>(Uw, UwT, ENC, ATT);
    trans_bf16<<<dim3((NGATES + 31) / 32, (EMB + 31) / 32), 256, 0, stream>>>(W_ih, WihT, EMB, NGATES);

    // u_hs = features @ Uw + Ub   (12544 x 512, K=2048), A f32 -> bf16 on the fly
    mfma_gemm<true, false><<<dim3(ATT / 128, (B * NF) / 128), 256, 0, stream>>>(
        (const void*)features, UwT, Ub, (void*)uhs, B * NF, ATT, ENC);
    // egate = embeds @ W_ih[:512] + (b_ih + b_hh)   (1536 x 2048, K=512), bf16 out
    mfma_gemm<false, true><<<dim3(NGATES / 128, (B * T) / 128), 256, 0, stream>>>(
        (const void*)emb16, WihT, bsum, (void*)egate, B * T, NGATES, EMB);

    // ---- recurrent loop ----
    for (int t = 0; t < T; ++t) {
        wah_kernel<<<B, 256, 0, stream>>>(h, Ww, Wb, wah);
        scores_kernel<<<dim3(7, B), 256, 0, stream>>>(uhs, wah, Aw, Ab, scores);
        smctx_kernel<<<dim3(ENC / 256, B), 256, 0, stream>>>(scores, features, ctx, alphas, t);
        gates_splitk<<<dim3(NGATES / 128, 1, NSPLIT), 256, 0, stream>>>(ctx, h, W_ih, W_hh, part);
        lstm_kernel<<<(B * DEC) / 256, 256, 0, stream>>>(part, egate, h, c, Hb16, t);
    }

    // ---- tail: transpose fcn_w into freed uhs/egate region, then preds GEMM ----
    trans_bf16<<<dim3((V + 31) / 32, (DEC + 31) / 32), 256, 0, stream>>>(fcn_w, fcnwT, DEC, V);
    mfma_gemm<false, false><<<dim3((V + 127) / 128, (B * T) / 128), 256, 0, stream>>>(
        (const void*)Hb16, fcnwT, fcn_b, (void*)preds, B * T, V, DEC);
}